// Round 17
// baseline (242.644 us; speedup 1.0000x reference)
//
#include <hip/hip_runtime.h>

#define P_N 2048
#define Q_N 512
#define A_N 48
#define WPTS 512         // points per wave
#define PPL 8            // points held per lane (WPTS/64)
#define CAP 13           // uint2 candidate slots per thread
// LDS: cand[256*13] uint2 = 26624 B; merge overlay needs 3*1024 uint2 = 3072 <= 3328 OK

// plain numpy-f32 3-term dot: ((x*x' + y*y') + z*z'), each op separately rounded
__device__ __forceinline__ float dot3_rn(float ax, float ay, float az,
                                         float bx, float by, float bz) {
    return __fadd_rn(__fadd_rn(__fmul_rn(ax, bx), __fmul_rn(ay, by)),
                     __fmul_rn(az, bz));
}

// XLA fused mul+reduce FMA chain: fma(z,z', fma(y,y', rn(x*x')))
__device__ __forceinline__ float dot3_fma(float ax, float ay, float az,
                                          float bx, float by, float bz) {
    return __fmaf_rn(az, bz, __fmaf_rn(ay, by, __fmul_rn(ax, bx)));
}

// sorted insert (ascending) into 16-entry register list; stable for equal keys
__device__ __forceinline__ void insert16(float d, int idx, float (&td)[16], int (&ti)[16]) {
    if (d >= td[15]) return;
    #pragma unroll
    for (int j = 15; j >= 1; --j) {
        float oldd = td[j]; int oldi = ti[j];
        bool up   = (d < td[j - 1]);
        bool here = (d < oldd);
        td[j] = up ? td[j - 1] : (here ? d : oldd);
        ti[j] = up ? ti[j - 1] : (here ? idx : oldi);
    }
    if (d < td[0]) { ti[0] = idx; td[0] = d; }
}

__device__ __forceinline__ float bcast(float v, int l) {
    return __uint_as_float(__builtin_amdgcn_readlane(__float_as_uint(v), l));
}

__global__ __launch_bounds__(256, 4) void aronet_kernel(
        const float* __restrict__ pcd, const float* __restrict__ qry,
        const float* __restrict__ anc, float* __restrict__ out) {
    __shared__ uint2 cand[256 * CAP];        // 26624 B; dead after scan -> merge bufs
    uint2* mbuf = cand;                      // merge overlay: buf w-1 at (w-1)*1024

    const int tid  = threadIdx.x;
    const int lane = tid & 63;
    const int w    = tid >> 6;               // wave 0..3

    const int bid = blockIdx.x;              // (b*48 + a)*8 + qc
    const int qc  = bid & 7;
    const int ba  = bid >> 3;                // 0..95
    const int a   = ba % A_N;
    const int b   = ba / A_N;

    const float ax = anc[(b * A_N + a) * 3 + 0];
    const float ay = anc[(b * A_N + a) * 3 + 1];
    const float az = anc[(b * A_N + a) * 3 + 2];

    // ---- each lane computes+holds 8 points of (dist, dir) in REGISTERS ----
    // verified profile: d2 plain, dist = sqrt_rn(d2), dir = vec * rn(1/dist)
    const float* pbase = pcd + (size_t)b * P_N * 3;
    const int pq0  = w * WPTS;               // wave's point-quarter base
    const int myp0 = pq0 + lane * PPL;       // this lane's 8 consecutive points
    float pd[PPL], pxv[PPL], pyv[PPL], pzv[PPL];
    #pragma unroll
    for (int s = 0; s < PPL; ++s) {
        const float* pp = pbase + (size_t)(myp0 + s) * 3;
        float vx = __fsub_rn(pp[0], ax);
        float vy = __fsub_rn(pp[1], ay);
        float vz = __fsub_rn(pp[2], az);
        float d2 = dot3_rn(vx, vy, vz, vx, vy, vz);
        float dist = __fsqrt_rn(d2);
        float r = __fdiv_rn(1.0f, dist);
        pd[s]  = dist;
        pxv[s] = __fmul_rn(vx, r);
        pyv[s] = __fmul_rn(vy, r);
        pzv[s] = __fmul_rn(vz, r);
    }

    // ---- per-lane query setup (identical math to passing kernel) ----
    const int q = (qc << 6) + lane;
    const float qx = qry[((size_t)b * Q_N + q) * 3 + 0];
    const float qy = qry[((size_t)b * Q_N + q) * 3 + 1];
    const float qz = qry[((size_t)b * Q_N + q) * 3 + 2];
    const float vqx = __fsub_rn(qx, ax);
    const float vqy = __fsub_rn(qy, ay);
    const float vqz = __fsub_rn(qz, az);
    const float qd2 = dot3_rn(vqx, vqy, vqz, vqx, vqy, vqz);
    const float qdist = __fsqrt_rn(qd2);
    const float qr = __fdiv_rn(1.0f, qdist);
    const float dqx = __fmul_rn(vqx, qr);
    const float dqy = __fmul_rn(vqy, qr);
    const float dqz = __fmul_rn(vqz, qr);

    const float COS_TH = 0.9659258262890683f;

    float td[16]; int ti[16];
    #pragma unroll
    for (int j = 0; j < 16; ++j) { td[j] = __builtin_inff(); ti[j] = 0; }

    // ---- scan: broadcast each point from holder lane via readlane (no memory) ----
    const int lbase = tid * CAP;
    int cnt = 0;
    for (int half = 0; half < 2; ++half) {           // 2 x 256-pt chunks (flush scope)
        for (int L = half * 32; L < half * 32 + 32; ++L) {   // holder lane, uniform
            #pragma unroll
            for (int s = 0; s < PPL; ++s) {
                float sd = bcast(pd[s],  L);
                float sx = bcast(pxv[s], L);
                float sy = bcast(pyv[s], L);
                float sz = bcast(pzv[s], L);
                float cosv = dot3_fma(dqx, dqy, dqz, sx, sy, sz);
                if (!(cosv <= COS_TH)) {             // candidate iff !(cos <= TH)
                    const int p = pq0 + L * PPL + s; // ascending point order
                    if (cnt < CAP) {
                        cand[lbase + cnt] = make_uint2(__float_as_uint(sd), (unsigned)p);
                        ++cnt;
                    } else {
                        insert16(sd, p, td, ti);     // overflow fallback (rare)
                    }
                }
            }
        }
        for (int k = 0; k < cnt; ++k) {              // chunk flush, ascending order
            uint2 e = cand[lbase + k];
            insert16(__uint_as_float(e.x), (int)e.y, td, ti);
        }
        cnt = 0;
    }

    // ---- serial merge (r16-proven): w1..w3 publish, w0 merges ascending ----
    __syncthreads();                                 // B1: cand lists dead
    if (w > 0) {
        uint2* mb = mbuf + (w - 1) * 1024;
        #pragma unroll
        for (int k = 0; k < 16; ++k)
            mb[k * 64 + lane] = make_uint2(__float_as_uint(td[k]), (unsigned)ti[k]);
    }
    __syncthreads();                                 // B2

    if (w == 0) {
        for (int w2 = 0; w2 < 3; ++w2) {             // ascending wave = ascending idx
            const uint2* mb = mbuf + w2 * 1024;
            #pragma unroll
            for (int k = 0; k < 16; ++k) {
                uint2 e = mb[k * 64 + lane];
                float d = __uint_as_float(e.x);
                if (d < __builtin_inff()) insert16(d, (int)e.y, td, ti);
            }
        }

        // ---- emit features: out[b][q][a][0..16][0..3] as float32 ----
        float4* o = (float4*)(out + (((size_t)(b * Q_N + q) * A_N + a) * 17) * 4);
        o[0] = make_float4(vqx, vqy, vqz, qdist);

        #pragma unroll
        for (int j = 0; j < 16; ++j) {
            float4 wv;
            if (td[j] == __builtin_inff()) {
                wv = make_float4(0.0f, 0.0f, 0.0f, 0.0f);   // padded -> exact zeros
            } else {
                const float* hp = pbase + (size_t)ti[j] * 3;
                float hx = __fsub_rn(hp[0], qx);
                float hy = __fsub_rn(hp[1], qy);
                float hz = __fsub_rn(hp[2], qz);
                float sq = dot3_rn(hx, hy, hz, hx, hy, hz);
                float md = (sq == 0.0f) ? 0.0f : __fsqrt_rn(sq);
                wv = make_float4(hx, hy, hz, md);
            }
            o[1 + j] = wv;
        }
    }
}

extern "C" void kernel_launch(void* const* d_in, const int* in_sizes, int n_in,
                              void* d_out, int out_size, void* d_ws, size_t ws_size,
                              hipStream_t stream) {
    const float* pcd = (const float*)d_in[0];
    const float* qry = (const float*)d_in[1];
    const float* anc = (const float*)d_in[2];
    float* out = (float*)d_out;

    dim3 grid(2 * A_N * 8);   // (b, anchor, 64-query chunk) = 768 blocks
    dim3 block(256);          // 4 waves: each owns a point-quarter in registers
    hipLaunchKernelGGL(aronet_kernel, grid, block, 0, stream, pcd, qry, anc, out);
}

// Round 18
// 198.758 us; speedup vs baseline: 1.2208x; 1.2208x over previous
//
#include <hip/hip_runtime.h>

#define P_N 2048
#define Q_N 512
#define A_N 48
#define NW 8             // waves per block
#define WPTS 256         // points per wave (contiguous slice)
#define CAP 24           // u8 candidate slots per thread (slice-local offsets)
#define LSTR 25          // cand stride in bytes

// plain numpy-f32 3-term dot: ((x*x' + y*y') + z*z'), each op separately rounded
__device__ __forceinline__ float dot3_rn(float ax, float ay, float az,
                                         float bx, float by, float bz) {
    return __fadd_rn(__fadd_rn(__fmul_rn(ax, bx), __fmul_rn(ay, by)),
                     __fmul_rn(az, bz));
}

// XLA fused mul+reduce FMA chain: fma(z,z', fma(y,y', rn(x*x')))
__device__ __forceinline__ float dot3_fma(float ax, float ay, float az,
                                          float bx, float by, float bz) {
    return __fmaf_rn(az, bz, __fmaf_rn(ay, by, __fmul_rn(ax, bx)));
}

// sorted insert (ascending) into 16-entry register list; stable for equal keys
__device__ __forceinline__ void insert16(float d, int idx, float (&td)[16], int (&ti)[16]) {
    if (d >= td[15]) return;
    #pragma unroll
    for (int j = 15; j >= 1; --j) {
        float oldd = td[j]; int oldi = ti[j];
        bool up   = (d < td[j - 1]);
        bool here = (d < oldd);
        td[j] = up ? td[j - 1] : (here ? d : oldd);
        ti[j] = up ? ti[j - 1] : (here ? idx : oldi);
    }
    if (d < td[0]) { ti[0] = idx; td[0] = d; }
}

__global__ __launch_bounds__(512, 3) void aronet_kernel(
        const float* __restrict__ pcd, const float* __restrict__ qry,
        const float* __restrict__ anc, float* __restrict__ out) {
    __shared__ float4 spt[P_N];                 // 32 KiB; dead after scan -> merge bufs
    __shared__ unsigned char cand[512 * LSTR];  // 12800 B candidate lists (u8 offsets)

    uint2* mbuf = (uint2*)spt;                  // merge view: buf j = mbuf[j*1024 ..)

    const int tid  = threadIdx.x;
    const int lane = tid & 63;
    const int w    = tid >> 6;                  // wave id 0..7

    const int bid = blockIdx.x;                 // (b*48 + a)*8 + qc
    const int qc  = bid & 7;
    const int ba  = bid >> 3;                   // 0..95
    const int a   = ba % A_N;
    const int b   = ba / A_N;

    const float ax = anc[ba * 3 + 0];
    const float ay = anc[ba * 3 + 1];
    const float az = anc[ba * 3 + 2];

    // ---- each wave stages ITS OWN 256-point slice (verified profile:
    //      d2 plain, dist = sqrt_rn(d2), dir = vec * rn(1/dist)) ----
    const float* pbase = pcd + (size_t)b * P_N * 3;
    const int pq0 = w * WPTS;
    for (int i = lane; i < WPTS; i += 64) {
        const int p = pq0 + i;
        float vx = __fsub_rn(pbase[p * 3 + 0], ax);
        float vy = __fsub_rn(pbase[p * 3 + 1], ay);
        float vz = __fsub_rn(pbase[p * 3 + 2], az);
        float d2 = dot3_rn(vx, vy, vz, vx, vy, vz);
        float dist = __fsqrt_rn(d2);
        float r = __fdiv_rn(1.0f, dist);
        spt[p] = make_float4(dist, __fmul_rn(vx, r), __fmul_rn(vy, r), __fmul_rn(vz, r));
    }

    // ---- per-lane query setup (identical math to passing kernel) ----
    const int q = (qc << 6) + lane;
    const float qx = qry[((size_t)b * Q_N + q) * 3 + 0];
    const float qy = qry[((size_t)b * Q_N + q) * 3 + 1];
    const float qz = qry[((size_t)b * Q_N + q) * 3 + 2];
    const float vqx = __fsub_rn(qx, ax);
    const float vqy = __fsub_rn(qy, ay);
    const float vqz = __fsub_rn(qz, az);
    const float qd2 = dot3_rn(vqx, vqy, vqz, vqx, vqy, vqz);
    const float qdist = __fsqrt_rn(qd2);
    const float qr = __fdiv_rn(1.0f, qdist);
    const float dqx = __fmul_rn(vqx, qr);
    const float dqy = __fmul_rn(vqy, qr);
    const float dqz = __fmul_rn(vqz, qr);

    const float COS_TH = 0.9659258262890683f;

    float td[16]; int ti[16];
    #pragma unroll
    for (int j = 0; j < 16; ++j) { td[j] = __builtin_inff(); ti[j] = 0; }

    // ---- scan own 256-pt slice (r16-proven internals, single flush scope) ----
    const int lbase = tid * LSTR;
    int cnt = 0;
    #pragma unroll 4
    for (int i = 0; i < WPTS; ++i) {
        const int p = pq0 + i;
        float4 pt = spt[p];                     // wave-uniform broadcast read
        float cosv = dot3_fma(dqx, dqy, dqz, pt.y, pt.z, pt.w);
        if (!(cosv <= COS_TH)) {                // candidate iff !(cos <= TH)
            if (cnt < CAP) { cand[lbase + cnt] = (unsigned char)i; cnt++; }
            else insert16(pt.x, p, td, ti);     // overflow fallback (P ~ 1e-11)
        }
    }
    for (int k = 0; k < cnt; ++k) {             // flush, ascending order preserved
        int i = pq0 + cand[lbase + k];
        insert16(spt[i].x, i, td, ti);
    }

    // ---- 3-level tree merge over 8 waves (VERBATIM r13 — passed) ----
    __syncthreads();                            // all scans/flushes done; spt dead
    if (w & 1) {                                // w1,3,5,7 -> bufs 0..3
        uint2* mb = mbuf + (w >> 1) * 1024;
        #pragma unroll
        for (int k = 0; k < 16; ++k)
            mb[k * 64 + lane] = make_uint2(__float_as_uint(td[k]), (unsigned)ti[k]);
    }
    __syncthreads();
    if (!(w & 1)) {                             // w0<-w1, w2<-w3, w4<-w5, w6<-w7
        const uint2* mb = mbuf + (w >> 1) * 1024;
        #pragma unroll
        for (int k = 0; k < 16; ++k) {
            uint2 e = mb[k * 64 + lane];
            float d = __uint_as_float(e.x);
            if (d < __builtin_inff()) insert16(d, (int)e.y, td, ti);
        }
    }
    __syncthreads();
    if (w == 2 || w == 6) {                     // republish: w2->buf0, w6->buf1
        uint2* mb = mbuf + (w >> 2) * 1024;
        #pragma unroll
        for (int k = 0; k < 16; ++k)
            mb[k * 64 + lane] = make_uint2(__float_as_uint(td[k]), (unsigned)ti[k]);
    }
    __syncthreads();
    if (w == 0 || w == 4) {                     // w0<-w2', w4<-w6'
        const uint2* mb = mbuf + (w >> 2) * 1024;
        #pragma unroll
        for (int k = 0; k < 16; ++k) {
            uint2 e = mb[k * 64 + lane];
            float d = __uint_as_float(e.x);
            if (d < __builtin_inff()) insert16(d, (int)e.y, td, ti);
        }
    }
    __syncthreads();
    if (w == 4) {                               // republish w4'' -> buf0
        uint2* mb = mbuf;
        #pragma unroll
        for (int k = 0; k < 16; ++k)
            mb[k * 64 + lane] = make_uint2(__float_as_uint(td[k]), (unsigned)ti[k]);
    }
    __syncthreads();

    if (w == 0) {
        const uint2* mb = mbuf;                 // final: w0 <- w4''
        #pragma unroll
        for (int k = 0; k < 16; ++k) {
            uint2 e = mb[k * 64 + lane];
            float d = __uint_as_float(e.x);
            if (d < __builtin_inff()) insert16(d, (int)e.y, td, ti);
        }

        // ---- emit features: out[b][q][a][0..16][0..3] as float32 ----
        float4* o = (float4*)(out + (((size_t)(b * Q_N + q) * A_N + a) * 17) * 4);
        o[0] = make_float4(vqx, vqy, vqz, qdist);

        #pragma unroll
        for (int j = 0; j < 16; ++j) {
            float4 wv;
            if (td[j] == __builtin_inff()) {
                wv = make_float4(0.0f, 0.0f, 0.0f, 0.0f);   // padded -> exact zeros
            } else {
                const float* hp = pbase + (size_t)ti[j] * 3;
                float hx = __fsub_rn(hp[0], qx);
                float hy = __fsub_rn(hp[1], qy);
                float hz = __fsub_rn(hp[2], qz);
                float sq = dot3_rn(hx, hy, hz, hx, hy, hz);
                float md = (sq == 0.0f) ? 0.0f : __fsqrt_rn(sq);
                wv = make_float4(hx, hy, hz, md);
            }
            o[1 + j] = wv;
        }
    }
}

extern "C" void kernel_launch(void* const* d_in, const int* in_sizes, int n_in,
                              void* d_out, int out_size, void* d_ws, size_t ws_size,
                              hipStream_t stream) {
    const float* pcd = (const float*)d_in[0];
    const float* qry = (const float*)d_in[1];
    const float* anc = (const float*)d_in[2];
    float* out = (float*)d_out;

    dim3 grid(2 * A_N * 8);   // (b, anchor, 64-query chunk) = 768 blocks
    dim3 block(512);          // 8 waves: each stages+scans a 256-point slice
    hipLaunchKernelGGL(aronet_kernel, grid, block, 0, stream, pcd, qry, anc, out);
}

// Round 19
// 194.688 us; speedup vs baseline: 1.2463x; 1.0209x over previous
//
#include <hip/hip_runtime.h>

#define P_N 2048
#define Q_N 512
#define A_N 48
#define WPTS 512         // points per wave
#define CHUNK 256
#define CAP 24           // u8 candidate slots per thread (chunk-local offsets)
#define LSTR 25          // cand stride in bytes

// plain numpy-f32 3-term dot: ((x*x' + y*y') + z*z'), each op separately rounded
__device__ __forceinline__ float dot3_rn(float ax, float ay, float az,
                                         float bx, float by, float bz) {
    return __fadd_rn(__fadd_rn(__fmul_rn(ax, bx), __fmul_rn(ay, by)),
                     __fmul_rn(az, bz));
}

// XLA fused mul+reduce FMA chain: fma(z,z', fma(y,y', rn(x*x')))
__device__ __forceinline__ float dot3_fma(float ax, float ay, float az,
                                          float bx, float by, float bz) {
    return __fmaf_rn(az, bz, __fmaf_rn(ay, by, __fmul_rn(ax, bx)));
}

// sorted insert (ascending) into 16-entry register list; stable for equal keys
__device__ __forceinline__ void insert16(float d, int idx, float (&td)[16], int (&ti)[16]) {
    if (d >= td[15]) return;
    #pragma unroll
    for (int j = 15; j >= 1; --j) {
        float oldd = td[j]; int oldi = ti[j];
        bool up   = (d < td[j - 1]);
        bool here = (d < oldd);
        td[j] = up ? td[j - 1] : (here ? d : oldd);
        ti[j] = up ? ti[j - 1] : (here ? idx : oldi);
    }
    if (d < td[0]) { ti[0] = idx; td[0] = d; }
}

__global__ __launch_bounds__(256, 4) void aronet_kernel(
        const float* __restrict__ pcd, const float* __restrict__ qry,
        const float* __restrict__ anc, float* __restrict__ out) {
    __shared__ float4 spt[P_N];                 // 32 KiB; dead after scan -> merge bufs
    __shared__ unsigned char cand[256 * LSTR];  // 6400 B candidate lists (u8 offsets)

    uint2* mbuf = (uint2*)spt;                  // merge overlay: buf w-1 at (w-1)*1024

    const int tid  = threadIdx.x;
    const int lane = tid & 63;
    const int w    = tid >> 6;                  // wave 0..3

    const int bid = blockIdx.x;                 // (b*48 + a)*8 + qc
    const int qc  = bid & 7;
    const int ba  = bid >> 3;                   // 0..95
    const int a   = ba % A_N;
    const int b   = ba / A_N;

    const float ax = anc[(b * A_N + a) * 3 + 0];
    const float ay = anc[(b * A_N + a) * 3 + 1];
    const float az = anc[(b * A_N + a) * 3 + 2];

    // ---- each wave stages ITS OWN point-quarter (verified profile:
    //      d2 plain, dist = sqrt_rn(d2), dir = vec * rn(1/dist)) ----
    const float* pbase = pcd + (size_t)b * P_N * 3;
    const int pq0 = w * WPTS;
    for (int i = lane; i < WPTS; i += 64) {
        const int p = pq0 + i;
        float vx = __fsub_rn(pbase[p * 3 + 0], ax);
        float vy = __fsub_rn(pbase[p * 3 + 1], ay);
        float vz = __fsub_rn(pbase[p * 3 + 2], az);
        float d2 = dot3_rn(vx, vy, vz, vx, vy, vz);
        float dist = __fsqrt_rn(d2);
        float r = __fdiv_rn(1.0f, dist);
        spt[p] = make_float4(dist, __fmul_rn(vx, r), __fmul_rn(vy, r), __fmul_rn(vz, r));
    }

    // ---- per-lane query setup (identical math to passing kernel) ----
    const int q = (qc << 6) + lane;
    const float qx = qry[((size_t)b * Q_N + q) * 3 + 0];
    const float qy = qry[((size_t)b * Q_N + q) * 3 + 1];
    const float qz = qry[((size_t)b * Q_N + q) * 3 + 2];
    const float vqx = __fsub_rn(qx, ax);
    const float vqy = __fsub_rn(qy, ay);
    const float vqz = __fsub_rn(qz, az);
    const float qd2 = dot3_rn(vqx, vqy, vqz, vqx, vqy, vqz);
    const float qdist = __fsqrt_rn(qd2);
    const float qr = __fdiv_rn(1.0f, qdist);
    const float dqx = __fmul_rn(vqx, qr);
    const float dqy = __fmul_rn(vqy, qr);
    const float dqz = __fmul_rn(vqz, qr);

    const float COS_TH = 0.9659258262890683f;

    float td[16]; int ti[16];
    #pragma unroll
    for (int j = 0; j < 16; ++j) { td[j] = __builtin_inff(); ti[j] = 0; }

    // ---- scan own quarter: batch-8 reads, then 8 tests (one latency window) ----
    const int lbase = tid * LSTR;
    int cnt = 0;

#define TESTPT(PT, POFF)                                                      \
    {                                                                         \
        float cosv = dot3_fma(dqx, dqy, dqz, (PT).y, (PT).z, (PT).w);         \
        if (!(cosv <= COS_TH)) {                                              \
            if (cnt < CAP) { cand[lbase + cnt] = (unsigned char)(POFF); cnt++; } \
            else insert16((PT).x, c0 + (POFF), td, ti);                       \
        }                                                                     \
    }

    for (int c0 = pq0; c0 < pq0 + WPTS; c0 += CHUNK) {
        for (int g = 0; g < CHUNK; g += 8) {
            float4 t0 = spt[c0 + g + 0];         // 8 ds_read_b128 back-to-back
            float4 t1 = spt[c0 + g + 1];
            float4 t2 = spt[c0 + g + 2];
            float4 t3 = spt[c0 + g + 3];
            float4 t4 = spt[c0 + g + 4];
            float4 t5 = spt[c0 + g + 5];
            float4 t6 = spt[c0 + g + 6];
            float4 t7 = spt[c0 + g + 7];
            TESTPT(t0, g + 0); TESTPT(t1, g + 1);
            TESTPT(t2, g + 2); TESTPT(t3, g + 3);
            TESTPT(t4, g + 4); TESTPT(t5, g + 5);
            TESTPT(t6, g + 6); TESTPT(t7, g + 7);
        }
        for (int k = 0; k < cnt; ++k) {          // flush, ascending order preserved
            int i = c0 + cand[lbase + k];
            insert16(spt[i].x, i, td, ti);
        }
        cnt = 0;
    }
#undef TESTPT

    // ---- serial merge (r16-proven): w1..w3 publish, w0 merges ascending ----
    __syncthreads();                             // B1: all spt reads done, spt dead
    if (w > 0) {
        uint2* mb = mbuf + (w - 1) * 1024;
        #pragma unroll
        for (int k = 0; k < 16; ++k)
            mb[k * 64 + lane] = make_uint2(__float_as_uint(td[k]), (unsigned)ti[k]);
    }
    __syncthreads();                             // B2

    if (w == 0) {
        for (int w2 = 0; w2 < 3; ++w2) {         // ascending wave = ascending index
            const uint2* mb = mbuf + w2 * 1024;
            #pragma unroll
            for (int k = 0; k < 16; ++k) {
                uint2 e = mb[k * 64 + lane];
                float d = __uint_as_float(e.x);
                if (d < __builtin_inff()) insert16(d, (int)e.y, td, ti);
            }
        }

        // ---- emit features: out[b][q][a][0..16][0..3] as float32 ----
        float4* o = (float4*)(out + (((size_t)(b * Q_N + q) * A_N + a) * 17) * 4);
        o[0] = make_float4(vqx, vqy, vqz, qdist);

        #pragma unroll
        for (int j = 0; j < 16; ++j) {
            float4 wv;
            if (td[j] == __builtin_inff()) {
                wv = make_float4(0.0f, 0.0f, 0.0f, 0.0f);   // padded -> exact zeros
            } else {
                const float* hp = pbase + (size_t)ti[j] * 3;
                float hx = __fsub_rn(hp[0], qx);
                float hy = __fsub_rn(hp[1], qy);
                float hz = __fsub_rn(hp[2], qz);
                float sq = dot3_rn(hx, hy, hz, hx, hy, hz);
                float md = (sq == 0.0f) ? 0.0f : __fsqrt_rn(sq);
                wv = make_float4(hx, hy, hz, md);
            }
            o[1 + j] = wv;
        }
    }
}

extern "C" void kernel_launch(void* const* d_in, const int* in_sizes, int n_in,
                              void* d_out, int out_size, void* d_ws, size_t ws_size,
                              hipStream_t stream) {
    const float* pcd = (const float*)d_in[0];
    const float* qry = (const float*)d_in[1];
    const float* anc = (const float*)d_in[2];
    float* out = (float*)d_out;

    dim3 grid(2 * A_N * 8);   // (b, anchor, 64-query chunk) = 768 blocks
    dim3 block(256);          // 4 waves: each stages+scans a point-quarter
    hipLaunchKernelGGL(aronet_kernel, grid, block, 0, stream, pcd, qry, anc, out);
}